// Round 4
// baseline (7699.563 us; speedup 1.0000x reference)
//
#include <hip/hip_runtime.h>
#include <hip/hip_bf16.h>

typedef __hip_bfloat16 bf16;
typedef __hip_bfloat162 bf162;

// Problem constants
static constexpr int Nn = 2, CIN = 128, Hh = 240, Ww = 320, HW = 76800;
static constexpr int Cc = 128, HEADS = 4, HD = 32, WSQ = 49;
static constexpr int HID = 512, DOUT = 256;
static constexpr int NWH = 35, NWW = 46, WPN = NWH * NWW;   // 1610 windows per image
static constexpr int NWIN = Nn * WPN;                        // 3220
static constexpr float SCALE = 0.17677669529663687f;         // 32^-0.5

__device__ __forceinline__ float bf2f(bf16 h) { return __bfloat162float(h); }

// load 8 consecutive f32 (16B aligned) via two float4
__device__ __forceinline__ void load8f(const float* p, float* f) {
  const float4 a = *(const float4*)p;
  const float4 b = *(const float4*)(p + 4);
  f[0] = a.x; f[1] = a.y; f[2] = a.z; f[3] = a.w;
  f[4] = b.x; f[5] = b.y; f[6] = b.z; f[7] = b.w;
}

// unpack 8 consecutive bf16 (16B aligned) into f32
__device__ __forceinline__ void unpack8(const bf16* p, float* f) {
  const uint4 w = *(const uint4*)p;
  f[0] = __uint_as_float(w.x << 16); f[1] = __uint_as_float(w.x & 0xffff0000u);
  f[2] = __uint_as_float(w.y << 16); f[3] = __uint_as_float(w.y & 0xffff0000u);
  f[4] = __uint_as_float(w.z << 16); f[5] = __uint_as_float(w.z & 0xffff0000u);
  f[6] = __uint_as_float(w.w << 16); f[7] = __uint_as_float(w.w & 0xffff0000u);
}

__global__ void init_head(float* headbuf) {
  if (threadIdx.x < 256) headbuf[threadIdx.x] = 0.f;
}

// 1x1 conv -> residual stream tok[n,hw,e] (f32, lives in d_out maps region)
__global__ __launch_bounds__(256) void conv_kernel(
    const float* __restrict__ x, const float* __restrict__ conv_w, const float* __restrict__ conv_b,
    float* __restrict__ tok) {
  __shared__ float wlds[128 * 128];  // wlds[c][e]
  const int tid = threadIdx.x;
  for (int idx = tid; idx < 16384; idx += 256) {
    const int e = idx & 127, c = idx >> 7;
    wlds[c * 128 + e] = conv_w[e * 128 + c];
  }
  __syncthreads();
  const int n = blockIdx.y;
  const int hw0 = blockIdx.x * 128;
  const int hwi = tid & 63, eg = tid >> 6;
  const float* xn = x + (size_t)n * CIN * HW + hw0 + hwi;
  float acc0[32], acc1[32];
#pragma unroll
  for (int jj = 0; jj < 32; jj++) {
    const float b = conv_b[eg * 32 + jj];
    acc0[jj] = b; acc1[jj] = b;
  }
  for (int c = 0; c < CIN; c++) {
    const float xv0 = xn[(size_t)c * HW];
    const float xv1 = xn[(size_t)c * HW + 64];
    const float* wl = wlds + c * 128 + eg * 32;  // wave-uniform -> LDS broadcast
#pragma unroll
    for (int jj = 0; jj < 8; jj++) {
      const float4 w4 = *(const float4*)(wl + jj * 4);
      acc0[jj*4+0] = fmaf(w4.x, xv0, acc0[jj*4+0]); acc1[jj*4+0] = fmaf(w4.x, xv1, acc1[jj*4+0]);
      acc0[jj*4+1] = fmaf(w4.y, xv0, acc0[jj*4+1]); acc1[jj*4+1] = fmaf(w4.y, xv1, acc1[jj*4+1]);
      acc0[jj*4+2] = fmaf(w4.z, xv0, acc0[jj*4+2]); acc1[jj*4+2] = fmaf(w4.z, xv1, acc1[jj*4+2]);
      acc0[jj*4+3] = fmaf(w4.w, xv0, acc0[jj*4+3]); acc1[jj*4+3] = fmaf(w4.w, xv1, acc1[jj*4+3]);
    }
  }
  float* tb0 = tok + ((size_t)n * HW + hw0 + hwi) * Cc + eg * 32;
  float* tb1 = tb0 + (size_t)64 * Cc;
#pragma unroll
  for (int jj = 0; jj < 8; jj++) {
    *(float4*)(tb0 + jj * 4) = make_float4(acc0[jj*4], acc0[jj*4+1], acc0[jj*4+2], acc0[jj*4+3]);
    *(float4*)(tb1 + jj * 4) = make_float4(acc1[jj*4], acc1[jj*4+1], acc1[jj*4+2], acc1[jj*4+3]);
  }
}

// Fused per-window attention: LN1 + qkv + softmax(QK^T)V + proj + residual RMW.
__global__ __launch_bounds__(256) void attn_kernel(
    float* __restrict__ tok,
    const float* __restrict__ n1_g, const float* __restrict__ n1_b,
    const float* __restrict__ qkv_w, const float* __restrict__ qkv_b,
    const float* __restrict__ proj_w, const float* __restrict__ proj_b,
    int layer) {
  __shared__ __align__(16) char smem[63904];
  float* xw    = (float*)smem;              // [49][128] f32 LN'd window (stages A-B)
  bf16*  obuf  = (bf16*)smem;               // [49][128] bf16 attention out (aliases xw)
  float* probs = (float*)(smem + 12544);    // [49][50]  f32 scores (aliases xw tail)
  bf16*  qkvb  = (bf16*)(smem + 25088);     // [3][49][132] bf16 q,k,v (q pre-scaled)
  float* partial = (float*)(smem + 25088);  // [49][128] f32 proj partials (aliases qkvb)

  const int tid = threadIdx.x;
  const int wi = blockIdx.x;
  const int n = wi / WPN;
  const int r = wi % WPN;
  const int wh = r / NWW, ww = r % NWW;

  // Stage A: gather window rows + LayerNorm (pad rows -> 0)
  {
    const int wave = tid >> 6, lane = tid & 63;
    for (int ti = wave; ti < WSQ; ti += 4) {
      const int hh = wh * 7 + ti / 7, wv = ww * 7 + ti % 7;
      const bool valid = (hh < Hh) && (wv < Ww);
      float2 v = make_float2(0.f, 0.f);
      if (valid) v = *(const float2*)(tok + ((size_t)n * HW + hh * Ww + wv) * Cc + 2 * lane);
      float s = v.x + v.y;
      float q = v.x * v.x + v.y * v.y;
#pragma unroll
      for (int m = 1; m < 64; m <<= 1) { s += __shfl_xor(s, m); q += __shfl_xor(q, m); }
      const float mean = s * (1.f / 128.f);
      const float rstd = rsqrtf(fmaxf(q * (1.f / 128.f) - mean * mean, 0.f) + 1e-5f);
      const int c = 2 * lane;
      float o0 = 0.f, o1 = 0.f;
      if (valid) {
        o0 = (v.x - mean) * rstd * n1_g[layer * Cc + c]     + n1_b[layer * Cc + c];
        o1 = (v.y - mean) * rstd * n1_g[layer * Cc + c + 1] + n1_b[layer * Cc + c + 1];
      }
      *(float2*)(xw + ti * Cc + c) = make_float2(o0, o1);
    }
  }
  __syncthreads();

  // Stage B: qkv = xw @ qkv_w^T + b
  for (int j = tid; j < 384; j += 256) {
    const int which = j >> 7, cc = j & 127;
    float acc[WSQ];
    const float bj = qkv_b[layer * 384 + j];
#pragma unroll
    for (int t = 0; t < WSQ; t++) acc[t] = bj;
    const float* wrow = qkv_w + ((size_t)layer * 384 + j) * Cc;
    for (int c0 = 0; c0 < Cc; c0 += 8) {
      float w8[8]; load8f(wrow + c0, w8);
#pragma unroll
      for (int t = 0; t < WSQ; t++) {
        const float4 a = *(const float4*)(xw + t * Cc + c0);
        const float4 b = *(const float4*)(xw + t * Cc + c0 + 4);
        float s = acc[t];
        s = fmaf(w8[0], a.x, s); s = fmaf(w8[1], a.y, s);
        s = fmaf(w8[2], a.z, s); s = fmaf(w8[3], a.w, s);
        s = fmaf(w8[4], b.x, s); s = fmaf(w8[5], b.y, s);
        s = fmaf(w8[6], b.z, s); s = fmaf(w8[7], b.w, s);
        acc[t] = s;
      }
    }
    const float scl = (which == 0) ? SCALE : 1.0f;
#pragma unroll
    for (int t = 0; t < WSQ; t++)
      qkvb[(which * WSQ + t) * 132 + cc] = __float2bfloat16(acc[t] * scl);
  }
  __syncthreads();

  // Stages C/D/E per head: scores -> softmax -> o = P @ V
  for (int h = 0; h < HEADS; h++) {
    for (int idx = tid; idx < WSQ * WSQ; idx += 256) {
      const int qi = idx / WSQ, kj = idx % WSQ;
      const bf162* qrow = (const bf162*)(qkvb + qi * 132 + h * HD);
      const bf162* krow = (const bf162*)(qkvb + (WSQ + kj) * 132 + h * HD);
      float s = 0.f;
#pragma unroll
      for (int d = 0; d < HD / 2; d++) {
        const float2 qf = __bfloat1622float2(qrow[d]);
        const float2 kf = __bfloat1622float2(krow[d]);
        s = fmaf(qf.x, kf.x, s); s = fmaf(qf.y, kf.y, s);
      }
      probs[qi * 50 + kj] = s;
    }
    __syncthreads();
    if (tid < WSQ) {
      float m = -1e30f;
      for (int j2 = 0; j2 < WSQ; j2++) m = fmaxf(m, probs[tid * 50 + j2]);
      float ssum = 0.f;
      for (int j2 = 0; j2 < WSQ; j2++) {
        const float e = __expf(probs[tid * 50 + j2] - m);
        probs[tid * 50 + j2] = e; ssum += e;
      }
      const float inv = 1.f / ssum;
      for (int j2 = 0; j2 < WSQ; j2++) probs[tid * 50 + j2] *= inv;
    }
    __syncthreads();
    for (int idx = tid; idx < WSQ * HD; idx += 256) {
      const int t = idx >> 5, d = idx & 31;
      float s = 0.f;
      for (int j2 = 0; j2 < WSQ; j2++)
        s = fmaf(probs[t * 50 + j2], bf2f(qkvb[(2 * WSQ + j2) * 132 + h * HD + d]), s);
      obuf[t * Cc + h * HD + d] = __float2bfloat16(s);
    }
    __syncthreads();
  }

  // Stage F: proj + residual RMW into tok (K split over 2 thread halves)
  {
    const int e = tid & 127, kh = tid >> 7;
    float acc[WSQ];
    const float bj = kh ? proj_b[layer * Cc + e] : 0.f;
#pragma unroll
    for (int t = 0; t < WSQ; t++) acc[t] = bj;
    const float* wrow = proj_w + ((size_t)layer * Cc + e) * Cc + kh * 64;
    for (int c0 = 0; c0 < 64; c0 += 8) {
      float w8[8]; load8f(wrow + c0, w8);
      const int cb = kh * 64 + c0;
#pragma unroll
      for (int t = 0; t < WSQ; t++) {
        float o8[8]; unpack8(obuf + t * Cc + cb, o8);
        float s = acc[t];
        s = fmaf(w8[0], o8[0], s); s = fmaf(w8[1], o8[1], s);
        s = fmaf(w8[2], o8[2], s); s = fmaf(w8[3], o8[3], s);
        s = fmaf(w8[4], o8[4], s); s = fmaf(w8[5], o8[5], s);
        s = fmaf(w8[6], o8[6], s); s = fmaf(w8[7], o8[7], s);
        acc[t] = s;
      }
    }
    if (kh == 0) {
#pragma unroll
      for (int t = 0; t < WSQ; t++) partial[t * 128 + e] = acc[t];
    }
    __syncthreads();
    if (kh == 1) {
      for (int t = 0; t < WSQ; t++) {
        const int hh = wh * 7 + t / 7, wv = ww * 7 + t % 7;
        if (hh < Hh && wv < Ww) {
          float* p = tok + ((size_t)n * HW + hh * Ww + wv) * Cc + e;
          *p += acc[t] + partial[t * 128 + e];
        }
      }
    }
  }
}

// Fused MLP: LN2 + fc1 + gelu + fc2 + residual RMW. 32 tokens per block.
__global__ __launch_bounds__(256) void mlp_kernel(
    float* __restrict__ tok,
    const float* __restrict__ n2_g, const float* __restrict__ n2_b,
    const float* __restrict__ fc1_w, const float* __restrict__ fc1_b,
    const float* __restrict__ fc2_w, const float* __restrict__ fc2_b,
    int layer) {
  __shared__ __align__(16) char ms[49664];
  float* lnb = (float*)ms;            // [32][130] f32 LN'd tokens
  float* red = (float*)ms;            // [32][128] fc2 partials (aliases lnb)
  bf16*  hid = (bf16*)(ms + 16640);   // [32][512] bf16 gelu(fc1)
  float* mu  = (float*)(ms + 49408);  // [32]
  float* rs  = (float*)(ms + 49536);  // [32]
  const int tid = threadIdx.x;
  const int t0 = blockIdx.x * 32;

  {
    const float4* src = (const float4*)(tok + (size_t)t0 * Cc);
    for (int idx = tid; idx < 32 * Cc / 4; idx += 256) {
      const float4 v = src[idx];
      const int t = idx >> 5, c = (idx & 31) * 4;
      lnb[t * 130 + c] = v.x; lnb[t * 130 + c + 1] = v.y;
      lnb[t * 130 + c + 2] = v.z; lnb[t * 130 + c + 3] = v.w;
    }
  }
  __syncthreads();
  if (tid < 32) {
    float s = 0.f, q = 0.f;
    for (int c = 0; c < Cc; c++) { const float v = lnb[tid * 130 + c]; s += v; q = fmaf(v, v, q); }
    const float m = s * (1.f / 128.f);
    mu[tid] = m;
    rs[tid] = rsqrtf(fmaxf(q * (1.f / 128.f) - m * m, 0.f) + 1e-5f);
  }
  __syncthreads();
  for (int idx = tid; idx < 32 * Cc; idx += 256) {
    const int t = idx >> 7, c = idx & 127;
    lnb[t * 130 + c] = (lnb[t * 130 + c] - mu[t]) * rs[t] * n2_g[layer * Cc + c]
                       + n2_b[layer * Cc + c];
  }
  __syncthreads();

  // fc1 + gelu: each thread owns output columns (tid, tid+256)
  {
    const int j0 = tid, j1 = tid + 256;
    float acc0[32], acc1[32];
    const float b0 = fc1_b[layer * HID + j0], b1 = fc1_b[layer * HID + j1];
#pragma unroll
    for (int t = 0; t < 32; t++) { acc0[t] = b0; acc1[t] = b1; }
    const float* w0 = fc1_w + ((size_t)layer * HID + j0) * Cc;
    const float* w1 = fc1_w + ((size_t)layer * HID + j1) * Cc;
    for (int c0 = 0; c0 < Cc; c0 += 8) {
      float a8[8], c8[8];
      load8f(w0 + c0, a8); load8f(w1 + c0, c8);
#pragma unroll
      for (int t = 0; t < 32; t++) {
        const float* lp = lnb + t * 130 + c0;
        const float2 p0 = *(const float2*)(lp);
        const float2 p1 = *(const float2*)(lp + 2);
        const float2 p2 = *(const float2*)(lp + 4);
        const float2 p3 = *(const float2*)(lp + 6);
        float s0 = acc0[t], s1 = acc1[t];
        s0 = fmaf(a8[0], p0.x, s0); s1 = fmaf(c8[0], p0.x, s1);
        s0 = fmaf(a8[1], p0.y, s0); s1 = fmaf(c8[1], p0.y, s1);
        s0 = fmaf(a8[2], p1.x, s0); s1 = fmaf(c8[2], p1.x, s1);
        s0 = fmaf(a8[3], p1.y, s0); s1 = fmaf(c8[3], p1.y, s1);
        s0 = fmaf(a8[4], p2.x, s0); s1 = fmaf(c8[4], p2.x, s1);
        s0 = fmaf(a8[5], p2.y, s0); s1 = fmaf(c8[5], p2.y, s1);
        s0 = fmaf(a8[6], p3.x, s0); s1 = fmaf(c8[6], p3.x, s1);
        s0 = fmaf(a8[7], p3.y, s0); s1 = fmaf(c8[7], p3.y, s1);
        acc0[t] = s0; acc1[t] = s1;
      }
    }
#pragma unroll
    for (int t = 0; t < 32; t++) {
      const float x0 = acc0[t], x1 = acc1[t];
      hid[t * HID + j0] = __float2bfloat16(0.5f * x0 * (1.f + erff(x0 * 0.70710678118654752f)));
      hid[t * HID + j1] = __float2bfloat16(0.5f * x1 * (1.f + erff(x1 * 0.70710678118654752f)));
    }
  }
  __syncthreads();

  // fc2 + residual RMW
  {
    const int j = tid & 127, kh = tid >> 7;
    float acc[32];
#pragma unroll
    for (int t = 0; t < 32; t++) acc[t] = 0.f;
    const float* w = fc2_w + ((size_t)layer * Cc + j) * HID + kh * 256;
    const bf16* hb = hid + kh * 256;
    for (int c0 = 0; c0 < 256; c0 += 8) {
      float w8[8]; load8f(w + c0, w8);
#pragma unroll
      for (int t = 0; t < 32; t++) {
        float h8[8]; unpack8(hb + t * HID + c0, h8);
        float s = acc[t];
        s = fmaf(w8[0], h8[0], s); s = fmaf(w8[1], h8[1], s);
        s = fmaf(w8[2], h8[2], s); s = fmaf(w8[3], h8[3], s);
        s = fmaf(w8[4], h8[4], s); s = fmaf(w8[5], h8[5], s);
        s = fmaf(w8[6], h8[6], s); s = fmaf(w8[7], h8[7], s);
        acc[t] = s;
      }
    }
    if (kh == 0) {
#pragma unroll
      for (int t = 0; t < 32; t++) red[t * 128 + j] = acc[t];
    }
    __syncthreads();
    if (kh == 1) {
      const float bj = fc2_b[layer * Cc + j];
      for (int t = 0; t < 32; t++) {
        float* p = tok + (size_t)(t0 + t) * Cc + j;
        *p += acc[t] + red[t * 128 + j] + bj;
      }
    }
  }
}

// head[n,c] = mean over 76800 tokens (partial sums + atomicAdd)
__global__ __launch_bounds__(256) void head_kernel(const float* __restrict__ tok,
                                                   float* __restrict__ headbuf) {
  const int n = blockIdx.x >> 6, slice = blockIdx.x & 63;
  const int c = threadIdx.x & 127, half = threadIdx.x >> 7;
  const float* base = tok + ((size_t)n * HW + slice * 1200 + half * 600) * Cc + c;
  float s = 0.f;
  for (int i = 0; i < 600; i++) s += base[(size_t)i * Cc];
  atomicAdd(&headbuf[n * 128 + c], s * (1.f / 76800.f));
}

// tiny 3-layer head MLP + normalize; one block per n
__global__ __launch_bounds__(256) void y_kernel(
    const float* __restrict__ headbuf,
    const float* __restrict__ r1_w, const float* __restrict__ r1_b,
    const float* __restrict__ r2_w, const float* __restrict__ r2_b,
    const float* __restrict__ r3_w, const float* __restrict__ r3_b,
    float* __restrict__ yout) {
  __shared__ float hb[128], y1[256], y2[256], red4[4];
  const int tid = threadIdx.x;
  const int n = blockIdx.x;
  if (tid < 128) hb[tid] = headbuf[n * 128 + tid];
  __syncthreads();
  {
    float s = r1_b[tid];
    const float* w = r1_w + (size_t)tid * 128;
    for (int c = 0; c < 128; c += 8) {
      float w8[8]; load8f(w + c, w8);
#pragma unroll
      for (int i = 0; i < 8; i++) s = fmaf(w8[i], hb[c + i], s);
    }
    y1[tid] = s >= 0.f ? s : 0.01f * s;
  }
  __syncthreads();
  {
    float s = r2_b[tid];
    const float* w = r2_w + (size_t)tid * 256;
    for (int c = 0; c < 256; c += 8) {
      float w8[8]; load8f(w + c, w8);
#pragma unroll
      for (int i = 0; i < 8; i++) s = fmaf(w8[i], y1[c + i], s);
    }
    y2[tid] = s >= 0.f ? s : 0.01f * s;
  }
  __syncthreads();
  float v;
  {
    float s = r3_b[tid];
    const float* w = r3_w + (size_t)tid * 256;
    for (int c = 0; c < 256; c += 8) {
      float w8[8]; load8f(w + c, w8);
#pragma unroll
      for (int i = 0; i < 8; i++) s = fmaf(w8[i], y2[c + i], s);
    }
    v = (s > 0.f ? s : 0.f) + 0.1f;
  }
  float t = v;
#pragma unroll
  for (int m = 1; m < 64; m <<= 1) t += __shfl_xor(t, m);
  if ((tid & 63) == 0) red4[tid >> 6] = t;
  __syncthreads();
  const float tot = red4[0] + red4[1] + red4[2] + red4[3];
  yout[n * DOUT + tid] = v / tot;
}

// qwx[n,c,q] = sum_e queries[n,q,e] * conv_w[e,c];  qb[n,q] = sum_e queries[n,q,e] * conv_b[e]
// (maps = queries @ (W x + b) = (queries W) x + queries b — eliminates xp entirely)
__global__ __launch_bounds__(256) void qprep_kernel(
    const float* __restrict__ tok, const float* __restrict__ conv_w, const float* __restrict__ conv_b,
    float* __restrict__ qwx, float* __restrict__ qb) {
  __shared__ float qs[16384];  // [q][e]
  const int tid = threadIdx.x;
  const int n = blockIdx.x;
  for (int idx = tid; idx < 16384; idx += 256)
    qs[idx] = tok[((size_t)n * HW + (idx >> 7)) * Cc + (idx & 127)];
  __syncthreads();
  const int c = tid & 127, qh = tid >> 7;
  float acc[64];
#pragma unroll
  for (int j = 0; j < 64; j++) acc[j] = 0.f;
  for (int e = 0; e < 128; e++) {
    const float w = conv_w[e * 128 + c];
    const float* qcol = qs + (qh * 64) * 128 + e;
#pragma unroll 8
    for (int j = 0; j < 64; j++) acc[j] = fmaf(qcol[j * 128], w, acc[j]);
  }
  float* dst = qwx + ((size_t)n * 128 + c) * 128 + qh * 64;
#pragma unroll
  for (int j = 0; j < 64; j++) dst[j] = acc[j];
  if (tid < 128) {
    float s = 0.f;
    for (int e = 0; e < 128; e++) s = fmaf(qs[tid * 128 + e], conv_b[e], s);
    qb[n * 128 + tid] = s;
  }
}

// maps[n,q,hw] = sum_c qwx[n,c,q] * x[n,c,hw] + qb[n,q]   (overwrites the token region)
__global__ __launch_bounds__(256) void maps_kernel(
    const float* __restrict__ x, const float* __restrict__ qwx, const float* __restrict__ qb,
    float* __restrict__ mout) {
  __shared__ float qlds[16384];  // [c][q]
  const int tid = threadIdx.x;
  const int n = blockIdx.y;
  for (int idx = tid; idx < 16384; idx += 256) qlds[idx] = qwx[(size_t)n * 16384 + idx];
  __syncthreads();
  const int hw0 = blockIdx.x * 128;
  const int hwi = tid & 63, qg = tid >> 6;
  const float* xb = x + (size_t)n * CIN * HW + hw0 + hwi;
  float acc0[32], acc1[32];
#pragma unroll
  for (int jj = 0; jj < 32; jj++) {
    const float b = qb[n * 128 + qg * 32 + jj];
    acc0[jj] = b; acc1[jj] = b;
  }
  for (int c = 0; c < Cc; c++) {
    const float xv0 = xb[(size_t)c * HW];
    const float xv1 = xb[(size_t)c * HW + 64];
    const float* ql = qlds + c * 128 + qg * 32;
#pragma unroll
    for (int jj = 0; jj < 8; jj++) {
      const float4 w4 = *(const float4*)(ql + jj * 4);
      acc0[jj*4+0] = fmaf(w4.x, xv0, acc0[jj*4+0]); acc1[jj*4+0] = fmaf(w4.x, xv1, acc1[jj*4+0]);
      acc0[jj*4+1] = fmaf(w4.y, xv0, acc0[jj*4+1]); acc1[jj*4+1] = fmaf(w4.y, xv1, acc1[jj*4+1]);
      acc0[jj*4+2] = fmaf(w4.z, xv0, acc0[jj*4+2]); acc1[jj*4+2] = fmaf(w4.z, xv1, acc1[jj*4+2]);
      acc0[jj*4+3] = fmaf(w4.w, xv0, acc0[jj*4+3]); acc1[jj*4+3] = fmaf(w4.w, xv1, acc1[jj*4+3]);
    }
  }
  float* mb = mout + ((size_t)n * 128 + qg * 32) * HW + hw0 + hwi;
#pragma unroll
  for (int jj = 0; jj < 32; jj++) {
    mb[(size_t)jj * HW]      = acc0[jj];
    mb[(size_t)jj * HW + 64] = acc1[jj];
  }
}

extern "C" void kernel_launch(void* const* d_in, const int* in_sizes, int n_in,
                              void* d_out, int out_size, void* d_ws, size_t ws_size,
                              hipStream_t stream) {
  const float* x      = (const float*)d_in[0];
  const float* conv_w = (const float*)d_in[1];
  const float* conv_b = (const float*)d_in[2];
  const float* n1_g   = (const float*)d_in[3];
  const float* n1_b   = (const float*)d_in[4];
  const float* qkv_w  = (const float*)d_in[5];
  const float* qkv_b  = (const float*)d_in[6];
  const float* proj_w = (const float*)d_in[7];
  const float* proj_b = (const float*)d_in[8];
  const float* n2_g   = (const float*)d_in[9];
  const float* n2_b   = (const float*)d_in[10];
  const float* fc1_w  = (const float*)d_in[11];
  const float* fc1_b  = (const float*)d_in[12];
  const float* fc2_w  = (const float*)d_in[13];
  const float* fc2_b  = (const float*)d_in[14];
  const float* r1_w   = (const float*)d_in[15];
  const float* r1_b   = (const float*)d_in[16];
  const float* r2_w   = (const float*)d_in[17];
  const float* r2_b   = (const float*)d_in[18];
  const float* r3_w   = (const float*)d_in[19];
  const float* r3_b   = (const float*)d_in[20];

  // f32 output. Token residual stream (2*76800*128 f32) lives in the d_out maps
  // region (exactly 19,660,800 f32); consumed (head, y, queries) before
  // maps_kernel overwrites it. ws use: ~130 KB.
  float* out = (float*)d_out;
  float* tok = out + 512;
  float* qwx = (float*)d_ws;            // 2*128*128 f32
  float* qb = qwx + 32768;              // 2*128 f32
  float* headbuf = qb + 256;            // 2*128 f32

  init_head<<<1, 256, 0, stream>>>(headbuf);
  conv_kernel<<<dim3(600, 2), 256, 0, stream>>>(x, conv_w, conv_b, tok);
  for (int l = 0; l < 4; l++) {
    attn_kernel<<<NWIN, 256, 0, stream>>>(tok, n1_g, n1_b, qkv_w, qkv_b, proj_w, proj_b, l);
    mlp_kernel<<<4800, 256, 0, stream>>>(tok, n2_g, n2_b, fc1_w, fc1_b, fc2_w, fc2_b, l);
  }
  head_kernel<<<128, 256, 0, stream>>>(tok, headbuf);
  y_kernel<<<2, 256, 0, stream>>>(headbuf, r1_w, r1_b, r2_w, r2_b, r3_w, r3_b, out);
  qprep_kernel<<<2, 256, 0, stream>>>(tok, conv_w, conv_b, qwx, qb);
  maps_kernel<<<dim3(600, 2), 256, 0, stream>>>(x, qwx, qb, out + 512);
}

// Round 5
// 2342.532 us; speedup vs baseline: 3.2869x; 3.2869x over previous
//
#include <hip/hip_runtime.h>
#include <hip/hip_bf16.h>

typedef __hip_bfloat16 bf16;

// Problem constants
static constexpr int Nn = 2, CIN = 128, Hh = 240, Ww = 320, HW = 76800;
static constexpr int Cc = 128, HID = 512, DOUT = 256, WSQ = 49;
static constexpr int NWH = 35, NWW = 46, WPN = NWH * NWW;   // 1610 windows per image
static constexpr int NWIN = Nn * WPN;                        // 3220
static constexpr float SCALE = 0.17677669529663687f;         // 32^-0.5

typedef __attribute__((ext_vector_type(8))) short s8;   // 8 bf16 = one MFMA A/B frag
typedef __attribute__((ext_vector_type(4))) short s4;   // packed 4-bf16 LDS write
typedef __attribute__((ext_vector_type(2))) short s2;
typedef __attribute__((ext_vector_type(4))) float f4;   // MFMA accumulator

__device__ __forceinline__ short f2bf(float x) {
  union { bf16 b; short s; } u; u.b = __float2bfloat16(x); return u.s;
}

#define MFMA(a, b, c) __builtin_amdgcn_mfma_f32_16x16x32_bf16((a), (b), (c), 0, 0, 0)

// ---------------- weight cast: f32 -> bf16 (once per launch) ----------------
__global__ __launch_bounds__(256) void cast_bf16(const float* __restrict__ src,
                                                 short* __restrict__ dst, int n) {
  const int i = (blockIdx.x * 256 + threadIdx.x) * 4;
  if (i < n) {
    const float4 v = *(const float4*)(src + i);
    s4 o; o[0] = f2bf(v.x); o[1] = f2bf(v.y); o[2] = f2bf(v.z); o[3] = f2bf(v.w);
    *(s4*)(dst + i) = o;
  }
}

__global__ void init_head(float* headbuf) {
  if (threadIdx.x < 256) headbuf[threadIdx.x] = 0.f;
}

// ---------------- 1x1 conv -> residual stream tok[n,hw,e] (f32, in d_out) ----------------
__global__ __launch_bounds__(256) void conv_kernel(
    const float* __restrict__ x, const float* __restrict__ conv_w, const float* __restrict__ conv_b,
    float* __restrict__ tok) {
  __shared__ float wlds[128 * 128];  // wlds[c][e]
  const int tid = threadIdx.x;
  for (int idx = tid; idx < 16384; idx += 256) {
    const int e = idx & 127, c = idx >> 7;
    wlds[c * 128 + e] = conv_w[e * 128 + c];
  }
  __syncthreads();
  const int n = blockIdx.y;
  const int hw0 = blockIdx.x * 128;
  const int hwi = tid & 63, eg = tid >> 6;
  const float* xn = x + (size_t)n * CIN * HW + hw0 + hwi;
  float acc0[32], acc1[32];
#pragma unroll
  for (int jj = 0; jj < 32; jj++) {
    const float b = conv_b[eg * 32 + jj];
    acc0[jj] = b; acc1[jj] = b;
  }
  for (int c = 0; c < CIN; c++) {
    const float xv0 = xn[(size_t)c * HW];
    const float xv1 = xn[(size_t)c * HW + 64];
    const float* wl = wlds + c * 128 + eg * 32;
#pragma unroll
    for (int jj = 0; jj < 8; jj++) {
      const float4 w4 = *(const float4*)(wl + jj * 4);
      acc0[jj*4+0] = fmaf(w4.x, xv0, acc0[jj*4+0]); acc1[jj*4+0] = fmaf(w4.x, xv1, acc1[jj*4+0]);
      acc0[jj*4+1] = fmaf(w4.y, xv0, acc0[jj*4+1]); acc1[jj*4+1] = fmaf(w4.y, xv1, acc1[jj*4+1]);
      acc0[jj*4+2] = fmaf(w4.z, xv0, acc0[jj*4+2]); acc1[jj*4+2] = fmaf(w4.z, xv1, acc1[jj*4+2]);
      acc0[jj*4+3] = fmaf(w4.w, xv0, acc0[jj*4+3]); acc1[jj*4+3] = fmaf(w4.w, xv1, acc1[jj*4+3]);
    }
  }
  float* tb0 = tok + ((size_t)n * HW + hw0 + hwi) * Cc + eg * 32;
  float* tb1 = tb0 + (size_t)64 * Cc;
#pragma unroll
  for (int jj = 0; jj < 8; jj++) {
    *(float4*)(tb0 + jj * 4) = make_float4(acc0[jj*4], acc0[jj*4+1], acc0[jj*4+2], acc0[jj*4+3]);
    *(float4*)(tb1 + jj * 4) = make_float4(acc1[jj*4], acc1[jj*4+1], acc1[jj*4+2], acc1[jj*4+3]);
  }
}

// ---------------- fused window attention, MFMA everywhere ----------------
// LDS (59,392 B -> 2 blocks/CU):
//   xwv[9216]      : xw bf16 [64][136] (LN'd tokens)  -> later vT bf16 [128][72]
//   qkp[4][5120]   : per-head slice: q [64][40] @0, k [64][40] @2560;
//                    later P bf16 [64][72] @0 (over q+k), then o [64][40] @2560.
__global__ __launch_bounds__(256, 2) void attn_kernel(
    float* __restrict__ tok,
    const float* __restrict__ n1_g, const float* __restrict__ n1_b,
    const short* __restrict__ wqkv, const float* __restrict__ qkv_b,
    const short* __restrict__ wproj, const float* __restrict__ proj_b,
    int layer) {
  __shared__ __align__(16) short xwv[9216];
  __shared__ __align__(16) short qkp[4][5120];

  const int tid = threadIdx.x;
  const int w = tid >> 6, lane = tid & 63;
  const int lq = lane >> 4, li = lane & 15;
  const int wi = blockIdx.x;
  const int n = wi / WPN;
  const int r0 = wi % WPN;
  const int wh = r0 / NWW, ww = r0 % NWW;

  const short* wqkv_l = wqkv + (size_t)layer * 384 * 128;
  const short* wproj_l = wproj + (size_t)layer * 128 * 128;

  // ---- Phase 1: gather + LayerNorm -> xw bf16 [64][136]; zero pad rows ----
  for (int ti = w; ti < WSQ; ti += 4) {
    const int hh = wh * 7 + ti / 7, wv = ww * 7 + ti % 7;
    const bool valid = (hh < Hh) && (wv < Ww);
    float2 v = make_float2(0.f, 0.f);
    if (valid) v = *(const float2*)(tok + ((size_t)n * HW + hh * Ww + wv) * Cc + 2 * lane);
    float s = v.x + v.y, q = v.x * v.x + v.y * v.y;
#pragma unroll
    for (int m = 1; m < 64; m <<= 1) { s += __shfl_xor(s, m); q += __shfl_xor(q, m); }
    const float mean = s * (1.f / 128.f);
    const float rstd = rsqrtf(fmaxf(q * (1.f / 128.f) - mean * mean, 0.f) + 1e-5f);
    const int c = 2 * lane;
    float o0 = 0.f, o1 = 0.f;
    if (valid) {
      o0 = (v.x - mean) * rstd * n1_g[layer * Cc + c]     + n1_b[layer * Cc + c];
      o1 = (v.y - mean) * rstd * n1_g[layer * Cc + c + 1] + n1_b[layer * Cc + c + 1];
    }
    s2 pk; pk[0] = f2bf(o0); pk[1] = f2bf(o1);
    *(s2*)(xwv + ti * 136 + c) = pk;
  }
  for (int idx = tid; idx < 15 * 136; idx += 256) {
    xwv[(49 + idx / 136) * 136 + (idx % 136)] = 0;
  }
  __syncthreads();

  // ---- Phase 2a: q,k transposed: D'[n][token] = wqkv . xw^T ----
  // wave strip n in [64w, 64w+64): w=0,1 -> q; w=2,3 -> k
  {
    const int n0 = 64 * w;
    f4 acc[4][4];
#pragma unroll
    for (int mt = 0; mt < 4; mt++)
#pragma unroll
      for (int nt = 0; nt < 4; nt++) acc[mt][nt] = f4{0.f, 0.f, 0.f, 0.f};
    for (int s = 0; s < 4; s++) {
      s8 a[4], b[4];
#pragma unroll
      for (int mt = 0; mt < 4; mt++)
        a[mt] = *(const s8*)(wqkv_l + (n0 + mt * 16 + li) * 128 + s * 32 + lq * 8);
#pragma unroll
      for (int nt = 0; nt < 4; nt++)
        b[nt] = *(const s8*)(xwv + (nt * 16 + li) * 136 + s * 32 + lq * 8);
#pragma unroll
      for (int mt = 0; mt < 4; mt++)
#pragma unroll
        for (int nt = 0; nt < 4; nt++) acc[mt][nt] = MFMA(a[mt], b[nt], acc[mt][nt]);
    }
    const bool isq = (w < 2);
    const float scl = isq ? SCALE : 1.f;
    const int koff = isq ? 0 : 2560;
#pragma unroll
    for (int mt = 0; mt < 4; mt++) {
      const int nbase = n0 + mt * 16 + lq * 4;            // qkv output row (r=0)
      const int hsel = (isq ? nbase : (nbase - 128)) >> 5;
      const int d0 = nbase & 31;
      const float4 bb = *(const float4*)(qkv_b + layer * 384 + nbase);
#pragma unroll
      for (int nt = 0; nt < 4; nt++) {
        const int tokn = nt * 16 + li;
        s4 pk;
        pk[0] = f2bf((acc[mt][nt][0] + bb.x) * scl);
        pk[1] = f2bf((acc[mt][nt][1] + bb.y) * scl);
        pk[2] = f2bf((acc[mt][nt][2] + bb.z) * scl);
        pk[3] = f2bf((acc[mt][nt][3] + bb.w) * scl);
        *(s4*)(qkp[hsel] + koff + tokn * 40 + d0) = pk;
      }
    }
  }

  // ---- Phase 2b: v straight: D[token][n] = xw . wqkv_v^T ; export vT[d][token] ----
  {
    const int n0v = 32 * w;
    f4 acc2[4][2];
#pragma unroll
    for (int mt = 0; mt < 4; mt++)
#pragma unroll
      for (int nt = 0; nt < 2; nt++) acc2[mt][nt] = f4{0.f, 0.f, 0.f, 0.f};
    for (int s = 0; s < 4; s++) {
      s8 a[4], b[2];
#pragma unroll
      for (int mt = 0; mt < 4; mt++)
        a[mt] = *(const s8*)(xwv + (mt * 16 + li) * 136 + s * 32 + lq * 8);
#pragma unroll
      for (int nt = 0; nt < 2; nt++)
        b[nt] = *(const s8*)(wqkv_l + (256 + n0v + nt * 16 + li) * 128 + s * 32 + lq * 8);
#pragma unroll
      for (int mt = 0; mt < 4; mt++)
#pragma unroll
        for (int nt = 0; nt < 2; nt++) acc2[mt][nt] = MFMA(a[mt], b[nt], acc2[mt][nt]);
    }
    __syncthreads();  // all xw reads + all q/k writes complete
    // vT over the xw region: vT[d][token], stride 72, packed token-runs
#pragma unroll
    for (int nt = 0; nt < 2; nt++) {
      const int d = n0v + nt * 16 + li;
      const float bv = qkv_b[layer * 384 + 256 + d];
#pragma unroll
      for (int mt = 0; mt < 4; mt++) {
        const int m0 = mt * 16 + lq * 4;
        s4 pk;
        pk[0] = f2bf(acc2[mt][nt][0] + bv);
        pk[1] = f2bf(acc2[mt][nt][1] + bv);
        pk[2] = f2bf(acc2[mt][nt][2] + bv);
        pk[3] = f2bf(acc2[mt][nt][3] + bv);
        *(s4*)(xwv + d * 72 + m0) = pk;
      }
    }
  }

  // ---- Phase 3: per-head (wave = head): S^T = K.Q^T -> softmax -> O^T = V^T.P^T ----
  {
    short* qbase = qkp[w];
    short* kbase = qkp[w] + 2560;
    s8 ak[4], bq[4];
#pragma unroll
    for (int kt = 0; kt < 4; kt++) ak[kt] = *(const s8*)(kbase + (kt * 16 + li) * 40 + lq * 8);
#pragma unroll
    for (int qt = 0; qt < 4; qt++) bq[qt] = *(const s8*)(qbase + (qt * 16 + li) * 40 + lq * 8);
    f4 sc[4][4];
#pragma unroll
    for (int kt = 0; kt < 4; kt++)
#pragma unroll
      for (int qt = 0; qt < 4; qt++) sc[kt][qt] = f4{0.f, 0.f, 0.f, 0.f};
#pragma unroll
    for (int kt = 0; kt < 4; kt++)
#pragma unroll
      for (int qt = 0; qt < 4; qt++) sc[kt][qt] = MFMA(ak[kt], bq[qt], sc[kt][qt]);
    // mask mfma-pad keys (>=49)
#pragma unroll
    for (int kt = 0; kt < 4; kt++)
#pragma unroll
      for (int r = 0; r < 4; r++)
        if (kt * 16 + lq * 4 + r >= WSQ) {
#pragma unroll
          for (int qt = 0; qt < 4; qt++) sc[kt][qt][r] = -1e30f;
        }
    float inv[4];
#pragma unroll
    for (int qt = 0; qt < 4; qt++) {
      float m = -1e30f;
#pragma unroll
      for (int kt = 0; kt < 4; kt++)
#pragma unroll
        for (int r = 0; r < 4; r++) m = fmaxf(m, sc[kt][qt][r]);
      m = fmaxf(m, __shfl_xor(m, 16));
      m = fmaxf(m, __shfl_xor(m, 32));
      float ssum = 0.f;
#pragma unroll
      for (int kt = 0; kt < 4; kt++)
#pragma unroll
        for (int r = 0; r < 4; r++) {
          const float e = __expf(sc[kt][qt][r] - m);
          sc[kt][qt][r] = e; ssum += e;
        }
      ssum += __shfl_xor(ssum, 16);
      ssum += __shfl_xor(ssum, 32);
      inv[qt] = 1.f / ssum;
    }
    // P[query][key] bf16, stride 72, packed key-runs (overwrites own q/k; after reads)
#pragma unroll
    for (int qt = 0; qt < 4; qt++) {
      const int qq = qt * 16 + li;
#pragma unroll
      for (int kt = 0; kt < 4; kt++) {
        s4 pk;
        pk[0] = f2bf(sc[kt][qt][0] * inv[qt]);
        pk[1] = f2bf(sc[kt][qt][1] * inv[qt]);
        pk[2] = f2bf(sc[kt][qt][2] * inv[qt]);
        pk[3] = f2bf(sc[kt][qt][3] * inv[qt]);
        *(s4*)(qbase + qq * 72 + kt * 16 + lq * 4) = pk;
      }
    }
    // PV transposed: O^T[d][query]
    f4 ov[2][4];
#pragma unroll
    for (int dt = 0; dt < 2; dt++)
#pragma unroll
      for (int qt = 0; qt < 4; qt++) ov[dt][qt] = f4{0.f, 0.f, 0.f, 0.f};
    for (int s = 0; s < 2; s++) {
      s8 av[2], bp[4];
#pragma unroll
      for (int dt = 0; dt < 2; dt++)
        av[dt] = *(const s8*)(xwv + (w * 32 + dt * 16 + li) * 72 + s * 32 + lq * 8);
#pragma unroll
      for (int qt = 0; qt < 4; qt++)
        bp[qt] = *(const s8*)(qbase + (qt * 16 + li) * 72 + s * 32 + lq * 8);
#pragma unroll
      for (int dt = 0; dt < 2; dt++)
#pragma unroll
        for (int qt = 0; qt < 4; qt++) ov[dt][qt] = MFMA(av[dt], bp[qt], ov[dt][qt]);
    }
    // o[token][d] bf16, stride 40, at slice offset 2560 (over dead P tail)
    short* ohb = qkp[w] + 2560;
#pragma unroll
    for (int dt = 0; dt < 2; dt++) {
      const int dl0 = dt * 16 + lq * 4;
#pragma unroll
      for (int qt = 0; qt < 4; qt++) {
        const int tokn = qt * 16 + li;
        s4 pk;
        pk[0] = f2bf(ov[dt][qt][0]);
        pk[1] = f2bf(ov[dt][qt][1]);
        pk[2] = f2bf(ov[dt][qt][2]);
        pk[3] = f2bf(ov[dt][qt][3]);
        *(s4*)(ohb + tokn * 40 + dl0) = pk;
      }
    }
  }
  __syncthreads();

  // ---- Phase 4: proj straight: D[token][c] = o . wproj^T ; residual RMW ----
  {
    const int n0p = 32 * w;
    f4 pa[4][2];
#pragma unroll
    for (int mt = 0; mt < 4; mt++)
#pragma unroll
      for (int nt = 0; nt < 2; nt++) pa[mt][nt] = f4{0.f, 0.f, 0.f, 0.f};
    for (int s = 0; s < 4; s++) {  // k-chunk s == head s (o stored per-head)
      s8 ao[4], bw[2];
#pragma unroll
      for (int mt = 0; mt < 4; mt++)
        ao[mt] = *(const s8*)(qkp[s] + 2560 + (mt * 16 + li) * 40 + lq * 8);
#pragma unroll
      for (int nt = 0; nt < 2; nt++)
        bw[nt] = *(const s8*)(wproj_l + (n0p + nt * 16 + li) * 128 + s * 32 + lq * 8);
#pragma unroll
      for (int mt = 0; mt < 4; mt++)
#pragma unroll
        for (int nt = 0; nt < 2; nt++) pa[mt][nt] = MFMA(ao[mt], bw[nt], pa[mt][nt]);
    }
#pragma unroll
    for (int nt = 0; nt < 2; nt++) {
      const int c = n0p + nt * 16 + li;
      const float pb = proj_b[layer * 128 + c];
#pragma unroll
      for (int mt = 0; mt < 4; mt++) {
#pragma unroll
        for (int r = 0; r < 4; r++) {
          const int m = mt * 16 + lq * 4 + r;
          if (m < WSQ) {
            const int hh = wh * 7 + m / 7, wv = ww * 7 + m % 7;
            if (hh < Hh && wv < Ww) {
              float* p = tok + ((size_t)n * HW + hh * Ww + wv) * Cc + c;
              *p += pa[mt][nt][r] + pb;
            }
          }
        }
      }
    }
  }
}

// ---------------- fused MLP, MFMA: LN2 + fc1(gelu) + fc2 + residual ----------------
// 32 tokens/block. LDS 50,176 B -> 3 blocks/CU.
//   region A [0,16896): lnb bf16 [32][136] -> later res f32 [32][132]
//   hid bf16 [32][520] @16896
__global__ __launch_bounds__(256, 2) void mlp_kernel(
    float* __restrict__ tok,
    const float* __restrict__ n2_g, const float* __restrict__ n2_b,
    const short* __restrict__ wfc1, const float* __restrict__ fc1_b,
    const short* __restrict__ wfc2, const float* __restrict__ fc2_b,
    int layer) {
  __shared__ __align__(16) char ms[50176];
  short* lnb = (short*)ms;
  float* res = (float*)ms;
  short* hid = (short*)(ms + 16896);

  const int tid = threadIdx.x;
  const int w = tid >> 6, lane = tid & 63;
  const int lq = lane >> 4, li = lane & 15;
  const int t0 = blockIdx.x * 32;
  const short* wfc1_l = wfc1 + (size_t)layer * 512 * 128;
  const short* wfc2_l = wfc2 + (size_t)layer * 128 * 512;

  // ---- Phase 1: LN -> lnb bf16 ----
#pragma unroll
  for (int i = 0; i < 8; i++) {
    const int tl = w * 8 + i;
    const float2 v = *(const float2*)(tok + (size_t)(t0 + tl) * Cc + 2 * lane);
    float s = v.x + v.y, q = v.x * v.x + v.y * v.y;
#pragma unroll
    for (int m = 1; m < 64; m <<= 1) { s += __shfl_xor(s, m); q += __shfl_xor(q, m); }
    const float mean = s * (1.f / 128.f);
    const float rstd = rsqrtf(fmaxf(q * (1.f / 128.f) - mean * mean, 0.f) + 1e-5f);
    const int c = 2 * lane;
    s2 pk;
    pk[0] = f2bf((v.x - mean) * rstd * n2_g[layer * Cc + c]     + n2_b[layer * Cc + c]);
    pk[1] = f2bf((v.y - mean) * rstd * n2_g[layer * Cc + c + 1] + n2_b[layer * Cc + c + 1]);
    *(s2*)(lnb + tl * 136 + c) = pk;
  }
  __syncthreads();

  // ---- Phase 2: fc1 transposed: H^T[h][token] = wfc1 . lnb^T ; gelu; pack hid[token][h] ----
  {
    const int h0 = 128 * w;
    f4 acc[8][2];
#pragma unroll
    for (int mt = 0; mt < 8; mt++)
#pragma unroll
      for (int nt = 0; nt < 2; nt++) acc[mt][nt] = f4{0.f, 0.f, 0.f, 0.f};
    for (int s = 0; s < 4; s++) {
      s8 a[8], b[2];
#pragma unroll
      for (int mt = 0; mt < 8; mt++)
        a[mt] = *(const s8*)(wfc1_l + (h0 + mt * 16 + li) * 128 + s * 32 + lq * 8);
#pragma unroll
      for (int nt = 0; nt < 2; nt++)
        b[nt] = *(const s8*)(lnb + (nt * 16 + li) * 136 + s * 32 + lq * 8);
#pragma unroll
      for (int mt = 0; mt < 8; mt++)
#pragma unroll
        for (int nt = 0; nt < 2; nt++) acc[mt][nt] = MFMA(a[mt], b[nt], acc[mt][nt]);
    }
#pragma unroll
    for (int mt = 0; mt < 8; mt++) {
      const int hb = h0 + mt * 16 + lq * 4;
      const float4 bb = *(const float4*)(fc1_b + layer * HID + hb);
#pragma unroll
      for (int nt = 0; nt < 2; nt++) {
        const int tokn = nt * 16 + li;
        float g[4];
        g[0] = acc[mt][nt][0] + bb.x; g[1] = acc[mt][nt][1] + bb.y;
        g[2] = acc[mt][nt][2] + bb.z; g[3] = acc[mt][nt][3] + bb.w;
        s4 pk;
#pragma unroll
        for (int r = 0; r < 4; r++)
          pk[r] = f2bf(0.5f * g[r] * (1.f + erff(g[r] * 0.70710678118654752f)));
        *(s4*)(hid + tokn * 520 + hb) = pk;
      }
    }
  }
  __syncthreads();

  // ---- Phase 3: fc2 transposed: R^T[c][token] = wfc2 . hid^T ; pack res f32 [token][c] ----
  {
    const int c0 = 32 * w;
    f4 acc[2][2];
#pragma unroll
    for (int mt = 0; mt < 2; mt++)
#pragma unroll
      for (int nt = 0; nt < 2; nt++) acc[mt][nt] = f4{0.f, 0.f, 0.f, 0.f};
    for (int s = 0; s < 16; s++) {
      s8 a[2], b[2];
#pragma unroll
      for (int mt = 0; mt < 2; mt++)
        a[mt] = *(const s8*)(wfc2_l + (c0 + mt * 16 + li) * 512 + s * 32 + lq * 8);
#pragma unroll
      for (int nt = 0; nt < 2; nt++)
        b[nt] = *(const s8*)(hid + (nt * 16 + li) * 520 + s * 32 + lq * 8);
#pragma unroll
      for (int mt = 0; mt < 2; mt++)
#pragma unroll
        for (int nt = 0; nt < 2; nt++) acc[mt][nt] = MFMA(a[mt], b[nt], acc[mt][nt]);
    }
    __syncthreads();  // lnb dead everywhere before res writes
#pragma unroll
    for (int mt = 0; mt < 2; mt++) {
      const int cb = c0 + mt * 16 + lq * 4;
      const float4 bb = *(const float4*)(fc2_b + layer * Cc + cb);
#pragma unroll
      for (int nt = 0; nt < 2; nt++) {
        const int tokn = nt * 16 + li;
        float4 rv;
        rv.x = acc[mt][nt][0] + bb.x; rv.y = acc[mt][nt][1] + bb.y;
        rv.z = acc[mt][nt][2] + bb.z; rv.w = acc[mt][nt][3] + bb.w;
        *(float4*)(res + tokn * 132 + cb) = rv;
      }
    }
  }
  __syncthreads();

  // ---- Phase 4: residual copy-out (coalesced) ----
  for (int idx = tid; idx < 32 * 32; idx += 256) {
    const int t = idx >> 5, c4 = (idx & 31) * 4;
    const float4 rv = *(const float4*)(res + t * 132 + c4);
    float* p = tok + (size_t)(t0 + t) * Cc + c4;
    const float4 g = *(const float4*)p;
    *(float4*)p = make_float4(g.x + rv.x, g.y + rv.y, g.z + rv.z, g.w + rv.w);
  }
}

// ---------------- head mean ----------------
__global__ __launch_bounds__(256) void head_kernel(const float* __restrict__ tok,
                                                   float* __restrict__ headbuf) {
  const int n = blockIdx.x >> 6, slice = blockIdx.x & 63;
  const int c = threadIdx.x & 127, half = threadIdx.x >> 7;
  const float* base = tok + ((size_t)n * HW + slice * 1200 + half * 600) * Cc + c;
  float s = 0.f;
  for (int i = 0; i < 600; i++) s += base[(size_t)i * Cc];
  atomicAdd(&headbuf[n * 128 + c], s * (1.f / 76800.f));
}

// ---------------- y head MLP ----------------
__global__ __launch_bounds__(256) void y_kernel(
    const float* __restrict__ headbuf,
    const float* __restrict__ r1_w, const float* __restrict__ r1_b,
    const float* __restrict__ r2_w, const float* __restrict__ r2_b,
    const float* __restrict__ r3_w, const float* __restrict__ r3_b,
    float* __restrict__ yout) {
  __shared__ float hb[128], y1[256], y2[256], red4[4];
  const int tid = threadIdx.x;
  const int n = blockIdx.x;
  if (tid < 128) hb[tid] = headbuf[n * 128 + tid];
  __syncthreads();
  {
    float s = r1_b[tid];
    const float* w = r1_w + (size_t)tid * 128;
    for (int c = 0; c < 128; c += 4) {
      const float4 w4 = *(const float4*)(w + c);
      s = fmaf(w4.x, hb[c], s); s = fmaf(w4.y, hb[c+1], s);
      s = fmaf(w4.z, hb[c+2], s); s = fmaf(w4.w, hb[c+3], s);
    }
    y1[tid] = s >= 0.f ? s : 0.01f * s;
  }
  __syncthreads();
  {
    float s = r2_b[tid];
    const float* w = r2_w + (size_t)tid * 256;
    for (int c = 0; c < 256; c += 4) {
      const float4 w4 = *(const float4*)(w + c);
      s = fmaf(w4.x, y1[c], s); s = fmaf(w4.y, y1[c+1], s);
      s = fmaf(w4.z, y1[c+2], s); s = fmaf(w4.w, y1[c+3], s);
    }
    y2[tid] = s >= 0.f ? s : 0.01f * s;
  }
  __syncthreads();
  float v;
  {
    float s = r3_b[tid];
    const float* w = r3_w + (size_t)tid * 256;
    for (int c = 0; c < 256; c += 4) {
      const float4 w4 = *(const float4*)(w + c);
      s = fmaf(w4.x, y2[c], s); s = fmaf(w4.y, y2[c+1], s);
      s = fmaf(w4.z, y2[c+2], s); s = fmaf(w4.w, y2[c+3], s);
    }
    v = (s > 0.f ? s : 0.f) + 0.1f;
  }
  float t = v;
#pragma unroll
  for (int m = 1; m < 64; m <<= 1) t += __shfl_xor(t, m);
  if ((tid & 63) == 0) red4[tid >> 6] = t;
  __syncthreads();
  const float tot = red4[0] + red4[1] + red4[2] + red4[3];
  yout[n * DOUT + tid] = v / tot;
}

// ---------------- maps prep: fold queries into conv weights ----------------
__global__ __launch_bounds__(256) void qprep_kernel(
    const float* __restrict__ tok, const float* __restrict__ conv_w, const float* __restrict__ conv_b,
    float* __restrict__ qwx, float* __restrict__ qb) {
  __shared__ float qs[16384];  // [q][e]
  const int tid = threadIdx.x;
  const int n = blockIdx.x;
  for (int idx = tid; idx < 16384; idx += 256)
    qs[idx] = tok[((size_t)n * HW + (idx >> 7)) * Cc + (idx & 127)];
  __syncthreads();
  const int c = tid & 127, qh = tid >> 7;
  float acc[64];
#pragma unroll
  for (int j = 0; j < 64; j++) acc[j] = 0.f;
  for (int e = 0; e < 128; e++) {
    const float w = conv_w[e * 128 + c];
    const float* qcol = qs + (qh * 64) * 128 + e;
#pragma unroll 8
    for (int j = 0; j < 64; j++) acc[j] = fmaf(qcol[j * 128], w, acc[j]);
  }
  float* dst = qwx + ((size_t)n * 128 + c) * 128 + qh * 64;
#pragma unroll
  for (int j = 0; j < 64; j++) dst[j] = acc[j];
  if (tid < 128) {
    float s = 0.f;
    for (int e = 0; e < 128; e++) s = fmaf(qs[tid * 128 + e], conv_b[e], s);
    qb[n * 128 + tid] = s;
  }
}

// ---------------- maps ----------------
__global__ __launch_bounds__(256) void maps_kernel(
    const float* __restrict__ x, const float* __restrict__ qwx, const float* __restrict__ qb,
    float* __restrict__ mout) {
  __shared__ float qlds[16384];  // [c][q]
  const int tid = threadIdx.x;
  const int n = blockIdx.y;
  for (int idx = tid; idx < 16384; idx += 256) qlds[idx] = qwx[(size_t)n * 16384 + idx];
  __syncthreads();
  const int hw0 = blockIdx.x * 128;
  const int hwi = tid & 63, qg = tid >> 6;
  const float* xb = x + (size_t)n * CIN * HW + hw0 + hwi;
  float acc0[32], acc1[32];
#pragma unroll
  for (int jj = 0; jj < 32; jj++) {
    const float b = qb[n * 128 + qg * 32 + jj];
    acc0[jj] = b; acc1[jj] = b;
  }
  for (int c = 0; c < Cc; c++) {
    const float xv0 = xb[(size_t)c * HW];
    const float xv1 = xb[(size_t)c * HW + 64];
    const float* ql = qlds + c * 128 + qg * 32;
#pragma unroll
    for (int jj = 0; jj < 8; jj++) {
      const float4 w4 = *(const float4*)(ql + jj * 4);
      acc0[jj*4+0] = fmaf(w4.x, xv0, acc0[jj*4+0]); acc1[jj*4+0] = fmaf(w4.x, xv1, acc1[jj*4+0]);
      acc0[jj*4+1] = fmaf(w4.y, xv0, acc0[jj*4+1]); acc1[jj*4+1] = fmaf(w4.y, xv1, acc1[jj*4+1]);
      acc0[jj*4+2] = fmaf(w4.z, xv0, acc0[jj*4+2]); acc1[jj*4+2] = fmaf(w4.z, xv1, acc1[jj*4+2]);
      acc0[jj*4+3] = fmaf(w4.w, xv0, acc0[jj*4+3]); acc1[jj*4+3] = fmaf(w4.w, xv1, acc1[jj*4+3]);
    }
  }
  float* mb = mout + ((size_t)n * 128 + qg * 32) * HW + hw0 + hwi;
#pragma unroll
  for (int jj = 0; jj < 32; jj++) {
    mb[(size_t)jj * HW]      = acc0[jj];
    mb[(size_t)jj * HW + 64] = acc1[jj];
  }
}

extern "C" void kernel_launch(void* const* d_in, const int* in_sizes, int n_in,
                              void* d_out, int out_size, void* d_ws, size_t ws_size,
                              hipStream_t stream) {
  const float* x      = (const float*)d_in[0];
  const float* conv_w = (const float*)d_in[1];
  const float* conv_b = (const float*)d_in[2];
  const float* n1_g   = (const float*)d_in[3];
  const float* n1_b   = (const float*)d_in[4];
  const float* qkv_w  = (const float*)d_in[5];
  const float* qkv_b  = (const float*)d_in[6];
  const float* proj_w = (const float*)d_in[7];
  const float* proj_b = (const float*)d_in[8];
  const float* n2_g   = (const float*)d_in[9];
  const float* n2_b   = (const float*)d_in[10];
  const float* fc1_w  = (const float*)d_in[11];
  const float* fc1_b  = (const float*)d_in[12];
  const float* fc2_w  = (const float*)d_in[13];
  const float* fc2_b  = (const float*)d_in[14];
  const float* r1_w   = (const float*)d_in[15];
  const float* r1_b   = (const float*)d_in[16];
  const float* r2_w   = (const float*)d_in[17];
  const float* r2_b   = (const float*)d_in[18];
  const float* r3_w   = (const float*)d_in[19];
  const float* r3_b   = (const float*)d_in[20];

  // Token residual stream (f32) lives in the d_out maps region; consumed before maps.
  float* out = (float*)d_out;
  float* tok = out + 512;

  // ws: bf16 weight copies (1.57 MB) + qwx/qb/headbuf
  char* ws = (char*)d_ws;
  short* wqkv = (short*)ws;                       // 4*384*128
  short* wproj = (short*)(ws + 393216);           // 4*128*128
  short* wfc1 = (short*)(ws + 524288);            // 4*512*128
  short* wfc2 = (short*)(ws + 1048576);           // 4*128*512
  float* qwx = (float*)(ws + 1572864);            // 2*128*128 f32
  float* qb = (float*)(ws + 1703936);             // 2*128
  float* headbuf = (float*)(ws + 1704960);        // 2*128

  cast_bf16<<<196608 / 1024, 256, 0, stream>>>(qkv_w, wqkv, 196608);
  cast_bf16<<<65536 / 1024, 256, 0, stream>>>(proj_w, wproj, 65536);
  cast_bf16<<<262144 / 1024, 256, 0, stream>>>(fc1_w, wfc1, 262144);
  cast_bf16<<<262144 / 1024, 256, 0, stream>>>(fc2_w, wfc2, 262144);
  init_head<<<1, 256, 0, stream>>>(headbuf);
  conv_kernel<<<dim3(600, 2), 256, 0, stream>>>(x, conv_w, conv_b, tok);
  for (int l = 0; l < 4; l++) {
    attn_kernel<<<NWIN, 256, 0, stream>>>(tok, n1_g, n1_b, wqkv, qkv_b, wproj, proj_b, l);
    mlp_kernel<<<4800, 256, 0, stream>>>(tok, n2_g, n2_b, wfc1, fc1_b, wfc2, fc2_b, l);
  }
  head_kernel<<<128, 256, 0, stream>>>(tok, headbuf);
  y_kernel<<<2, 256, 0, stream>>>(headbuf, r1_w, r1_b, r2_w, r2_b, r3_w, r3_b, out);
  qprep_kernel<<<2, 256, 0, stream>>>(tok, conv_w, conv_b, qwx, qb);
  maps_kernel<<<dim3(600, 2), 256, 0, stream>>>(x, qwx, qb, out + 512);
}